// Round 2
// baseline (7653.386 us; speedup 1.0000x reference)
//
#include <hip/hip_runtime.h>
#include <math.h>

// Problem constants
#define B_    32
#define CIN   4
#define SLEN  2048
#define NF    256
#define HD    256          // LSTM hidden per direction
#define SP    341          // post conv+pool sequence length
#define RTOT  (B_*SP)      // 10912 rows
#define NH_   8
#define DH_   64

__device__ __forceinline__ float sigmoidf_(float x) { return 1.0f / (1.0f + expf(-x)); }

// ---------------------------------------------------------------------------
// Kernel 1: Conv1d(4->256,k13,pad6) + BN(eval) + ReLU + MaxPool1d(6) -> x0[b*341+s][co]
// ---------------------------------------------------------------------------
__global__ __launch_bounds__(256)
void conv_pool_k(const float* __restrict__ in, const float* __restrict__ cw,
                 const float* __restrict__ gamma, const float* __restrict__ beta,
                 float* __restrict__ x0)
{
    const int b  = blockIdx.y;
    const int s0 = blockIdx.x * 16;
    const int co = threadIdx.x;
    __shared__ float ins[CIN][16*6 + 12];   // [4][108] input window (with halo), zero-padded
    for (int idx = threadIdx.x; idx < CIN*108; idx += 256) {
        int ci = idx / 108, o = idx % 108;
        int pos = 6*s0 - 6 + o;
        ins[ci][o] = (pos >= 0 && pos < SLEN) ? in[(b*CIN + ci)*SLEN + pos] : 0.0f;
    }
    float wreg[52];
    {
        const float4* wp = (const float4*)(cw + co*52);   // 52 floats, 16B aligned
        #pragma unroll
        for (int j4 = 0; j4 < 13; ++j4) {
            float4 w4 = wp[j4];
            wreg[j4*4+0]=w4.x; wreg[j4*4+1]=w4.y; wreg[j4*4+2]=w4.z; wreg[j4*4+3]=w4.w;
        }
    }
    const float scale = gamma[co] * (1.0f / sqrtf(1.0f + 1e-5f));
    const float shift = beta[co];
    __syncthreads();
    for (int si = 0; si < 16; ++si) {
        int s = s0 + si;
        if (s >= SP) break;
        float win[CIN][18];
        #pragma unroll
        for (int ci = 0; ci < CIN; ++ci)
            #pragma unroll
            for (int o = 0; o < 18; ++o)
                win[ci][o] = ins[ci][6*si + o];
        float m = -1e30f;
        #pragma unroll
        for (int p6 = 0; p6 < 6; ++p6) {
            float acc = 0.0f;
            #pragma unroll
            for (int ci = 0; ci < CIN; ++ci)
                #pragma unroll
                for (int kk = 0; kk < 13; ++kk)
                    acc += win[ci][p6+kk] * wreg[ci*13+kk];
            float val = acc * scale + shift;
            val = fmaxf(val, 0.0f);
            m = fmaxf(m, val);
        }
        x0[(size_t)(b*SP + s)*NF + co] = m;
    }
}

// ---------------------------------------------------------------------------
// Kernel 2: generic fp32 GEMM  C[M,N] = act(A[M,K] @ Bw[N,K]^T + bias[N])
// ---------------------------------------------------------------------------
template<int RELU>
__global__ __launch_bounds__(256)
void gemm_k(const float* __restrict__ A, const float* __restrict__ Bw,
            const float* __restrict__ bias, float* __restrict__ C,
            int M, int N, int K)
{
    const int n0 = blockIdx.x * 128;
    const int m0 = blockIdx.y * 128;
    const int tid = threadIdx.x;
    const int tx = tid % 16, ty = tid / 16;
    __shared__ float As[16][132];
    __shared__ float Bs[16][132];
    float acc[8][8];
    #pragma unroll
    for (int i = 0; i < 8; ++i)
        #pragma unroll
        for (int j = 0; j < 8; ++j) acc[i][j] = 0.0f;

    const int lr = tid >> 1;         // 0..127
    const int lc = (tid & 1) * 8;    // 0 or 8

    for (int k0 = 0; k0 < K; k0 += 16) {
        {
            int gm = m0 + lr; if (gm >= M) gm = M - 1;     // clamp (dup rows, stores guarded)
            const float* ap = A + (size_t)gm*K + k0 + lc;
            float4 v0 = *(const float4*)ap;
            float4 v1 = *(const float4*)(ap + 4);
            As[lc+0][lr]=v0.x; As[lc+1][lr]=v0.y; As[lc+2][lr]=v0.z; As[lc+3][lr]=v0.w;
            As[lc+4][lr]=v1.x; As[lc+5][lr]=v1.y; As[lc+6][lr]=v1.z; As[lc+7][lr]=v1.w;
            const float* bp = Bw + (size_t)(n0 + lr)*K + k0 + lc;   // N always %128==0
            float4 u0 = *(const float4*)bp;
            float4 u1 = *(const float4*)(bp + 4);
            Bs[lc+0][lr]=u0.x; Bs[lc+1][lr]=u0.y; Bs[lc+2][lr]=u0.z; Bs[lc+3][lr]=u0.w;
            Bs[lc+4][lr]=u1.x; Bs[lc+5][lr]=u1.y; Bs[lc+6][lr]=u1.z; Bs[lc+7][lr]=u1.w;
        }
        __syncthreads();
        #pragma unroll
        for (int k = 0; k < 16; ++k) {
            float4 a0 = *(const float4*)&As[k][ty*4];
            float4 a1 = *(const float4*)&As[k][ty*4 + 64];
            float4 b0 = *(const float4*)&Bs[k][tx*4];
            float4 b1 = *(const float4*)&Bs[k][tx*4 + 64];
            float av[8] = {a0.x,a0.y,a0.z,a0.w,a1.x,a1.y,a1.z,a1.w};
            float bv[8] = {b0.x,b0.y,b0.z,b0.w,b1.x,b1.y,b1.z,b1.w};
            #pragma unroll
            for (int i = 0; i < 8; ++i)
                #pragma unroll
                for (int j = 0; j < 8; ++j)
                    acc[i][j] += av[i] * bv[j];
        }
        __syncthreads();
    }
    #pragma unroll
    for (int ih = 0; ih < 2; ++ih) {
        #pragma unroll
        for (int ii = 0; ii < 4; ++ii) {
            int m = m0 + ih*64 + ty*4 + ii;
            if (m >= M) continue;
            #pragma unroll
            for (int jh = 0; jh < 2; ++jh) {
                int n = n0 + jh*64 + tx*4;
                float4 bb = *(const float4*)&bias[n];
                float4 r;
                r.x = acc[ih*4+ii][jh*4+0] + bb.x;
                r.y = acc[ih*4+ii][jh*4+1] + bb.y;
                r.z = acc[ih*4+ii][jh*4+2] + bb.z;
                r.w = acc[ih*4+ii][jh*4+3] + bb.w;
                if (RELU) {
                    r.x = fmaxf(r.x, 0.f); r.y = fmaxf(r.y, 0.f);
                    r.z = fmaxf(r.z, 0.f); r.w = fmaxf(r.w, 0.f);
                }
                *(float4*)&C[(size_t)m*N + n] = r;
            }
        }
    }
}

// ---------------------------------------------------------------------------
// Kernel 3: one LSTM step (both directions)
// ---------------------------------------------------------------------------
__global__ __launch_bounds__(256)
void lstm_step_k(const float* __restrict__ G,     // [RTOT][2048]
                 const float* __restrict__ Whh,   // [2][1024][256]
                 const float* __restrict__ h_in,  // [2][341][256]
                 float* __restrict__ h_out,
                 float* __restrict__ c_st,
                 float* __restrict__ x_out,       // [RTOT][512]
                 int s)
{
    const int d = blockIdx.z;
    const int t_in = d ? (B_ - 1 - s) : s;
    const int n0 = blockIdx.y * 32;
    const int j0 = blockIdx.x * 32;
    const int tid = threadIdx.x;
    const int tx = tid % 16, ty = tid / 16;
    __shared__ float hs[32][68];
    __shared__ float ws[128][68];
    float acc[2][2][4];
    #pragma unroll
    for (int a = 0; a < 2; ++a)
        #pragma unroll
        for (int c = 0; c < 2; ++c)
            #pragma unroll
            for (int g = 0; g < 4; ++g) acc[a][c][g] = 0.0f;

    for (int k0 = 0; k0 < 256; k0 += 64) {
        {   // stage h tile [32][64]
            int r = tid >> 3, c8 = (tid & 7) * 8;
            int n = n0 + r; if (n > SP-1) n = SP-1;
            const float* hp = h_in + ((size_t)d*SP + n)*HD + k0 + c8;
            float4 v0 = *(const float4*)hp;
            float4 v1 = *(const float4*)(hp + 4);
            *(float4*)&hs[r][c8]   = v0;
            *(float4*)&hs[r][c8+4] = v1;
        }
        {   // stage Whh tile [128 gate-cols][64]
            int jr = tid >> 1, half = tid & 1;
            int g = jr >> 5, jl = jr & 31;
            int jc = g*256 + j0 + jl;
            const float* wp = Whh + ((size_t)d*1024 + jc)*HD + k0 + half*32;
            #pragma unroll
            for (int u4 = 0; u4 < 8; ++u4)
                *(float4*)&ws[jr][half*32 + u4*4] = *(const float4*)(wp + u4*4);
        }
        __syncthreads();
        #pragma unroll
        for (int k = 0; k < 64; k += 4) {
            float4 a0 = *(const float4*)&hs[ty][k];
            float4 a1 = *(const float4*)&hs[ty+16][k];
            #pragma unroll
            for (int g = 0; g < 4; ++g) {
                float4 b0 = *(const float4*)&ws[g*32 + tx][k];
                float4 b1 = *(const float4*)&ws[g*32 + tx + 16][k];
                acc[0][0][g] += a0.x*b0.x + a0.y*b0.y + a0.z*b0.z + a0.w*b0.w;
                acc[0][1][g] += a0.x*b1.x + a0.y*b1.y + a0.z*b1.z + a0.w*b1.w;
                acc[1][0][g] += a1.x*b0.x + a1.y*b0.y + a1.z*b0.z + a1.w*b0.w;
                acc[1][1][g] += a1.x*b1.x + a1.y*b1.y + a1.z*b1.z + a1.w*b1.w;
            }
        }
        __syncthreads();
    }
    #pragma unroll
    for (int ni = 0; ni < 2; ++ni) {
        int n = n0 + ty + ni*16;
        if (n >= SP) continue;
        #pragma unroll
        for (int ji = 0; ji < 2; ++ji) {
            int j = j0 + tx + ji*16;
            size_t gb = ((size_t)t_in*SP + n)*2048 + (size_t)d*1024;
            float gi = acc[ni][ji][0] + G[gb + j];
            float gf = acc[ni][ji][1] + G[gb + 256 + j];
            float gg = acc[ni][ji][2] + G[gb + 512 + j];
            float go = acc[ni][ji][3] + G[gb + 768 + j];
            size_t ci_ = ((size_t)d*SP + n)*HD + j;
            float c_old = c_st[ci_];
            float cn = sigmoidf_(gf)*c_old + sigmoidf_(gi)*tanhf(gg);
            float hn = sigmoidf_(go)*tanhf(cn);
            c_st[ci_] = cn;
            h_out[ci_] = hn;
            x_out[((size_t)t_in*SP + n)*512 + d*HD + j] = hn;
        }
    }
}

// ---------------------------------------------------------------------------
// Kernel 4 (REWRITTEN, spill-free): attention for one (head, batch, 16-q tile).
// scores = (q.k/8) / rpe -> softmax -> relu(P@V / sum) -> cat[r][h*64+d]
// RPE analytically: maxpool9x9/s6/p1 of |k-q|/2047 == max(|c1-r0|,|r1-c0|)/2047.
// Phases: QK (2q x 2k cols/thread), softmax (16 lanes/row), PV (1q x 4 dims/thread).
// LDS 45 KB -> 3 blocks/CU. K/V staged in 64-row chunks, stride-72 padding
// (288 B: 16B-aligned float4, conflict-free for both column- and dim-indexed reads).
// ---------------------------------------------------------------------------
__global__ __launch_bounds__(256)
void attn_k(const float* __restrict__ q, const float* __restrict__ k,
            const float* __restrict__ v, float* __restrict__ cat)
{
    const int h = blockIdx.z, b = blockIdx.y;
    const int q0 = blockIdx.x * 16;
    const int tid = threadIdx.x;
    __shared__ float qs[16][72];
    __shared__ float ks[64][72];    // k chunk, reused as v chunk in PV
    __shared__ float sc[16][348];
    __shared__ float rsum[16];

    {   // stage q tile [16][64]: one float4 per thread
        int r = tid >> 4, c4 = (tid & 15) * 4;
        int qq = q0 + r; if (qq > SP-1) qq = SP-1;
        *(float4*)&qs[r][c4] = *(const float4*)&q[((size_t)b*SP + qq)*512 + h*64 + c4];
    }

    const int tx = tid & 31;        // k-col within chunk (and +32)
    const int ty = tid >> 5;        // q-row pair (rows 2ty, 2ty+1)

    // ---- Phase 1: scores ----
    for (int p = 0; p < 6; ++p) {
        const int kk0 = p * 64;
        {   // stage k chunk [64][64]: 4 float4 per thread, one row each
            int jr = tid >> 2, c16 = (tid & 3) * 16;
            int kr = kk0 + jr;
            if (kr < SP) {
                const float* kp = &k[((size_t)b*SP + kr)*512 + h*64 + c16];
                #pragma unroll
                for (int u = 0; u < 4; ++u)
                    *(float4*)&ks[jr][c16 + u*4] = *(const float4*)(kp + u*4);
            } else {
                float4 z = {0.f,0.f,0.f,0.f};
                #pragma unroll
                for (int u = 0; u < 4; ++u)
                    *(float4*)&ks[jr][c16 + u*4] = z;
            }
        }
        __syncthreads();
        float acc00 = 0.f, acc01 = 0.f, acc10 = 0.f, acc11 = 0.f;
        #pragma unroll 4
        for (int d4 = 0; d4 < 64; d4 += 4) {
            float4 a0 = *(const float4*)&qs[2*ty][d4];
            float4 a1 = *(const float4*)&qs[2*ty+1][d4];
            float4 b0 = *(const float4*)&ks[tx][d4];
            float4 b1 = *(const float4*)&ks[tx+32][d4];
            acc00 += a0.x*b0.x + a0.y*b0.y + a0.z*b0.z + a0.w*b0.w;
            acc01 += a0.x*b1.x + a0.y*b1.y + a0.z*b1.z + a0.w*b1.w;
            acc10 += a1.x*b0.x + a1.y*b0.y + a1.z*b0.z + a1.w*b0.w;
            acc11 += a1.x*b1.x + a1.y*b1.y + a1.z*b1.z + a1.w*b1.w;
        }
        #pragma unroll
        for (int i = 0; i < 2; ++i) {
            int qq = q0 + 2*ty + i;
            int r0 = 6*qq - 1; if (r0 < 0) r0 = 0;
            int r1 = 6*qq + 7; if (r1 > SLEN-1) r1 = SLEN-1;
            float a0 = (i == 0) ? acc00 : acc10;
            float a1 = (i == 0) ? acc01 : acc11;
            #pragma unroll
            for (int j = 0; j < 2; ++j) {
                int kk = kk0 + tx + j*32;
                if (kk < SP) {
                    int c0 = 6*kk - 1; if (c0 < 0) c0 = 0;
                    int c1 = 6*kk + 7;                      // kk<=340 -> <=2047
                    int dd1 = c1 - r0; if (dd1 < 0) dd1 = -dd1;
                    int dd2 = r1 - c0; if (dd2 < 0) dd2 = -dd2;
                    int den = dd1 > dd2 ? dd1 : dd2;
                    sc[2*ty+i][kk] = ((j == 0 ? a0 : a1) * 0.125f) * 2047.0f / (float)den;
                }
            }
        }
        __syncthreads();
    }

    // ---- Phase 2: softmax (exp kept in sc, 1/sum folded into epilogue) ----
    {
        int row = tid >> 4, sub = tid & 15;
        float m = -1e30f;
        for (int kk = sub; kk < SP; kk += 16) m = fmaxf(m, sc[row][kk]);
        #pragma unroll
        for (int o = 1; o < 16; o <<= 1) m = fmaxf(m, __shfl_xor(m, o, 64));
        float ssum = 0.0f;
        for (int kk = sub; kk < SP; kk += 16) {
            float e = expf(sc[row][kk] - m);
            sc[row][kk] = e;
            ssum += e;
        }
        #pragma unroll
        for (int o = 1; o < 16; o <<= 1) ssum += __shfl_xor(ssum, o, 64);
        if (sub == 0) rsum[row] = ssum;
        if (tid < 48) { int rr = tid / 3, cc = SP + tid % 3; sc[rr][cc] = 0.0f; }  // zero cols 341..343
    }
    __syncthreads();

    // ---- Phase 3: PV. thread = (row pr, 4 contiguous dims pc) ----
    const int pr = tid >> 4;
    const int pc = (tid & 15) * 4;
    float o0 = 0.f, o1 = 0.f, o2 = 0.f, o3 = 0.f;
    for (int p = 0; p < 6; ++p) {
        const int kk0 = p * 64;
        {   // stage v chunk [64][64]
            int jr = tid >> 2, c16 = (tid & 3) * 16;
            int kr = kk0 + jr;
            if (kr < SP) {
                const float* vp = &v[((size_t)b*SP + kr)*512 + h*64 + c16];
                #pragma unroll
                for (int u = 0; u < 4; ++u)
                    *(float4*)&ks[jr][c16 + u*4] = *(const float4*)(vp + u*4);
            } else {
                float4 z = {0.f,0.f,0.f,0.f};
                #pragma unroll
                for (int u = 0; u < 4; ++u)
                    *(float4*)&ks[jr][c16 + u*4] = z;
            }
        }
        __syncthreads();
        int len = 344 - kk0; if (len > 64) len = 64;
        for (int kk = 0; kk < len; kk += 4) {
            float4 s = *(const float4*)&sc[pr][kk0 + kk];
            float sv[4] = {s.x, s.y, s.z, s.w};
            #pragma unroll
            for (int u = 0; u < 4; ++u) {
                float4 vv = *(const float4*)&ks[kk + u][pc];
                o0 += sv[u]*vv.x; o1 += sv[u]*vv.y; o2 += sv[u]*vv.z; o3 += sv[u]*vv.w;
            }
        }
        __syncthreads();
    }
    {
        int qq = q0 + pr;
        if (qq < SP) {
            float inv = 1.0f / rsum[pr];
            float4 r;
            r.x = fmaxf(o0*inv, 0.0f);
            r.y = fmaxf(o1*inv, 0.0f);
            r.z = fmaxf(o2*inv, 0.0f);
            r.w = fmaxf(o3*inv, 0.0f);
            *(float4*)&cat[((size_t)b*SP + qq)*512 + h*64 + pc] = r;
        }
    }
}

// ---------------------------------------------------------------------------
extern "C" void kernel_launch(void* const* d_in, const int* in_sizes, int n_in,
                              void* d_out, int out_size, void* d_ws, size_t ws_size,
                              hipStream_t stream)
{
    (void)in_sizes; (void)n_in; (void)out_size; (void)ws_size;
    const float* in    = (const float*)d_in[0];
    const float* cw    = (const float*)d_in[1];
    const float* gamma = (const float*)d_in[2];
    const float* beta  = (const float*)d_in[3];
    const float* Wih0  = (const float*)d_in[4];
    const float* Whh0  = (const float*)d_in[5];
    const float* b0    = (const float*)d_in[6];
    const float* Wih1  = (const float*)d_in[7];
    const float* Whh1  = (const float*)d_in[8];
    const float* b1    = (const float*)d_in[9];
    const float* Qw    = (const float*)d_in[10];
    const float* Qb    = (const float*)d_in[11];
    const float* Kw    = (const float*)d_in[12];
    const float* Kb    = (const float*)d_in[13];
    const float* Vw    = (const float*)d_in[14];
    const float* Vb    = (const float*)d_in[15];
    const float* mhw   = (const float*)d_in[16];
    const float* mhb   = (const float*)d_in[17];
    float* out = (float*)d_out;

    // workspace arena (floats). Total ~147 MB.
    float* x0 = (float*)d_ws;                                   //  2,793,472
    float* G  = x0 + (size_t)RTOT*NF;                           // 22,347,776 (reused for q,k,v)
    float* x1 = G  + (size_t)RTOT*2048;                         //  5,586,944 (reused for cat)
    float* x2 = x1 + (size_t)RTOT*512;                          //  5,586,944
    float* hb = x2 + (size_t)RTOT*512;                          //  2 * 174,592 (h double buffer)
    float* cb = hb + (size_t)2*2*SP*HD;                         //  174,592
    float* qbuf = G;
    float* kbuf = G + (size_t)RTOT*512;
    float* vbuf = G + (size_t)2*RTOT*512;
    float* cat  = x1;
    const size_t hsz = (size_t)2*SP*HD;

    // 1. conv+bn+relu+pool
    conv_pool_k<<<dim3(22, B_), 256, 0, stream>>>(in, cw, gamma, beta, x0);
    // 2. layer-1 input gates: G = x0 @ Wih0^T + b0   [10912 x 2048], K=256
    gemm_k<0><<<dim3(16, 86), 256, 0, stream>>>(x0, Wih0, b0, G, RTOT, 2048, 256);
    // 3. layer-1 scan (32 steps, both dirs)
    hipMemsetAsync(hb, 0, 2*hsz*sizeof(float), stream);
    hipMemsetAsync(cb, 0, hsz*sizeof(float), stream);
    for (int s = 0; s < B_; ++s) {
        float* hin  = hb + (size_t)(s & 1) * hsz;
        float* hout = hb + (size_t)((s+1) & 1) * hsz;
        lstm_step_k<<<dim3(8, 11, 2), 256, 0, stream>>>(G, Whh0, hin, hout, cb, x1, s);
    }
    // 4. layer-2 input gates: G = x1 @ Wih1^T + b1, K=512
    gemm_k<0><<<dim3(16, 86), 256, 0, stream>>>(x1, Wih1, b1, G, RTOT, 2048, 512);
    // 5. layer-2 scan
    hipMemsetAsync(hb, 0, 2*hsz*sizeof(float), stream);
    hipMemsetAsync(cb, 0, hsz*sizeof(float), stream);
    for (int s = 0; s < B_; ++s) {
        float* hin  = hb + (size_t)(s & 1) * hsz;
        float* hout = hb + (size_t)((s+1) & 1) * hsz;
        lstm_step_k<<<dim3(8, 11, 2), 256, 0, stream>>>(G, Whh1, hin, hout, cb, x2, s);
    }
    // 6. Q/K/V projections (flattened per-head weights are plain [512][512] GEMMs)
    gemm_k<0><<<dim3(4, 86), 256, 0, stream>>>(x2, Qw, Qb, qbuf, RTOT, 512, 512);
    gemm_k<0><<<dim3(4, 86), 256, 0, stream>>>(x2, Kw, Kb, kbuf, RTOT, 512, 512);
    gemm_k<0><<<dim3(4, 86), 256, 0, stream>>>(x2, Vw, Vb, vbuf, RTOT, 512, 512);
    // 7. relative-position attention + relu -> cat
    attn_k<<<dim3(22, B_, NH_), 256, 0, stream>>>(qbuf, kbuf, vbuf, cat);
    // 8. final linear + relu -> out
    gemm_k<1><<<dim3(4, 86), 256, 0, stream>>>(cat, mhw, mhb, out, RTOT, 512, 512);
}

// Round 3
// 2704.515 us; speedup vs baseline: 2.8299x; 2.8299x over previous
//
#include <hip/hip_runtime.h>
#include <math.h>

// Problem constants
#define B_    32
#define CIN   4
#define SLEN  2048
#define NF    256
#define HD    256          // LSTM hidden per direction
#define SP    341          // post conv+pool sequence length
#define RTOT  (B_*SP)      // 10912 rows
#define NH_   8
#define DH_   64
#define GRP   4            // batches per attention group
#define PSTR  344          // padded P row stride (16B-aligned)

__device__ __forceinline__ float sigmoidf_(float x) { return 1.0f / (1.0f + expf(-x)); }

// ---------------------------------------------------------------------------
// Kernel 1: Conv1d(4->256,k13,pad6) + BN(eval) + ReLU + MaxPool1d(6) -> x0[b*341+s][co]
// ---------------------------------------------------------------------------
__global__ __launch_bounds__(256)
void conv_pool_k(const float* __restrict__ in, const float* __restrict__ cw,
                 const float* __restrict__ gamma, const float* __restrict__ beta,
                 float* __restrict__ x0)
{
    const int b  = blockIdx.y;
    const int s0 = blockIdx.x * 16;
    const int co = threadIdx.x;
    __shared__ float ins[CIN][16*6 + 12];   // [4][108] input window (with halo), zero-padded
    for (int idx = threadIdx.x; idx < CIN*108; idx += 256) {
        int ci = idx / 108, o = idx % 108;
        int pos = 6*s0 - 6 + o;
        ins[ci][o] = (pos >= 0 && pos < SLEN) ? in[(b*CIN + ci)*SLEN + pos] : 0.0f;
    }
    float wreg[52];
    {
        const float4* wp = (const float4*)(cw + co*52);   // 52 floats, 16B aligned
        #pragma unroll
        for (int j4 = 0; j4 < 13; ++j4) {
            float4 w4 = wp[j4];
            wreg[j4*4+0]=w4.x; wreg[j4*4+1]=w4.y; wreg[j4*4+2]=w4.z; wreg[j4*4+3]=w4.w;
        }
    }
    const float scale = gamma[co] * (1.0f / sqrtf(1.0f + 1e-5f));
    const float shift = beta[co];
    __syncthreads();
    for (int si = 0; si < 16; ++si) {
        int s = s0 + si;
        if (s >= SP) break;
        float win[CIN][18];
        #pragma unroll
        for (int ci = 0; ci < CIN; ++ci)
            #pragma unroll
            for (int o = 0; o < 18; ++o)
                win[ci][o] = ins[ci][6*si + o];
        float m = -1e30f;
        #pragma unroll
        for (int p6 = 0; p6 < 6; ++p6) {
            float acc = 0.0f;
            #pragma unroll
            for (int ci = 0; ci < CIN; ++ci)
                #pragma unroll
                for (int kk = 0; kk < 13; ++kk)
                    acc += win[ci][p6+kk] * wreg[ci*13+kk];
            float val = acc * scale + shift;
            val = fmaxf(val, 0.0f);
            m = fmaxf(m, val);
        }
        x0[(size_t)(b*SP + s)*NF + co] = m;
    }
}

// ---------------------------------------------------------------------------
// Kernel 2: generic fp32 GEMM  C[M,N] = act(A[M,K] @ Bw[N,K]^T + bias[N])
// ---------------------------------------------------------------------------
template<int RELU>
__global__ __launch_bounds__(256)
void gemm_k(const float* __restrict__ A, const float* __restrict__ Bw,
            const float* __restrict__ bias, float* __restrict__ C,
            int M, int N, int K)
{
    const int n0 = blockIdx.x * 128;
    const int m0 = blockIdx.y * 128;
    const int tid = threadIdx.x;
    const int tx = tid % 16, ty = tid / 16;
    __shared__ float As[16][132];
    __shared__ float Bs[16][132];
    float acc[8][8];
    #pragma unroll
    for (int i = 0; i < 8; ++i)
        #pragma unroll
        for (int j = 0; j < 8; ++j) acc[i][j] = 0.0f;

    const int lr = tid >> 1;         // 0..127
    const int lc = (tid & 1) * 8;    // 0 or 8

    for (int k0 = 0; k0 < K; k0 += 16) {
        {
            int gm = m0 + lr; if (gm >= M) gm = M - 1;     // clamp (dup rows, stores guarded)
            const float* ap = A + (size_t)gm*K + k0 + lc;
            float4 v0 = *(const float4*)ap;
            float4 v1 = *(const float4*)(ap + 4);
            As[lc+0][lr]=v0.x; As[lc+1][lr]=v0.y; As[lc+2][lr]=v0.z; As[lc+3][lr]=v0.w;
            As[lc+4][lr]=v1.x; As[lc+5][lr]=v1.y; As[lc+6][lr]=v1.z; As[lc+7][lr]=v1.w;
            const float* bp = Bw + (size_t)(n0 + lr)*K + k0 + lc;   // N always %128==0
            float4 u0 = *(const float4*)bp;
            float4 u1 = *(const float4*)(bp + 4);
            Bs[lc+0][lr]=u0.x; Bs[lc+1][lr]=u0.y; Bs[lc+2][lr]=u0.z; Bs[lc+3][lr]=u0.w;
            Bs[lc+4][lr]=u1.x; Bs[lc+5][lr]=u1.y; Bs[lc+6][lr]=u1.z; Bs[lc+7][lr]=u1.w;
        }
        __syncthreads();
        #pragma unroll
        for (int k = 0; k < 16; ++k) {
            float4 a0 = *(const float4*)&As[k][ty*4];
            float4 a1 = *(const float4*)&As[k][ty*4 + 64];
            float4 b0 = *(const float4*)&Bs[k][tx*4];
            float4 b1 = *(const float4*)&Bs[k][tx*4 + 64];
            float av[8] = {a0.x,a0.y,a0.z,a0.w,a1.x,a1.y,a1.z,a1.w};
            float bv[8] = {b0.x,b0.y,b0.z,b0.w,b1.x,b1.y,b1.z,b1.w};
            #pragma unroll
            for (int i = 0; i < 8; ++i)
                #pragma unroll
                for (int j = 0; j < 8; ++j)
                    acc[i][j] += av[i] * bv[j];
        }
        __syncthreads();
    }
    #pragma unroll
    for (int ih = 0; ih < 2; ++ih) {
        #pragma unroll
        for (int ii = 0; ii < 4; ++ii) {
            int m = m0 + ih*64 + ty*4 + ii;
            if (m >= M) continue;
            #pragma unroll
            for (int jh = 0; jh < 2; ++jh) {
                int n = n0 + jh*64 + tx*4;
                float4 bb = *(const float4*)&bias[n];
                float4 r;
                r.x = acc[ih*4+ii][jh*4+0] + bb.x;
                r.y = acc[ih*4+ii][jh*4+1] + bb.y;
                r.z = acc[ih*4+ii][jh*4+2] + bb.z;
                r.w = acc[ih*4+ii][jh*4+3] + bb.w;
                if (RELU) {
                    r.x = fmaxf(r.x, 0.f); r.y = fmaxf(r.y, 0.f);
                    r.z = fmaxf(r.z, 0.f); r.w = fmaxf(r.w, 0.f);
                }
                *(float4*)&C[(size_t)m*N + n] = r;
            }
        }
    }
}

// ---------------------------------------------------------------------------
// Kernel 3: one LSTM step (both directions)
// ---------------------------------------------------------------------------
__global__ __launch_bounds__(256)
void lstm_step_k(const float* __restrict__ G,     // [RTOT][2048]
                 const float* __restrict__ Whh,   // [2][1024][256]
                 const float* __restrict__ h_in,  // [2][341][256]
                 float* __restrict__ h_out,
                 float* __restrict__ c_st,
                 float* __restrict__ x_out,       // [RTOT][512]
                 int s)
{
    const int d = blockIdx.z;
    const int t_in = d ? (B_ - 1 - s) : s;
    const int n0 = blockIdx.y * 32;
    const int j0 = blockIdx.x * 32;
    const int tid = threadIdx.x;
    const int tx = tid % 16, ty = tid / 16;
    __shared__ float hs[32][68];
    __shared__ float ws[128][68];
    float acc[2][2][4];
    #pragma unroll
    for (int a = 0; a < 2; ++a)
        #pragma unroll
        for (int c = 0; c < 2; ++c)
            #pragma unroll
            for (int g = 0; g < 4; ++g) acc[a][c][g] = 0.0f;

    for (int k0 = 0; k0 < 256; k0 += 64) {
        {   // stage h tile [32][64]
            int r = tid >> 3, c8 = (tid & 7) * 8;
            int n = n0 + r; if (n > SP-1) n = SP-1;
            const float* hp = h_in + ((size_t)d*SP + n)*HD + k0 + c8;
            float4 v0 = *(const float4*)hp;
            float4 v1 = *(const float4*)(hp + 4);
            *(float4*)&hs[r][c8]   = v0;
            *(float4*)&hs[r][c8+4] = v1;
        }
        {   // stage Whh tile [128 gate-cols][64]
            int jr = tid >> 1, half = tid & 1;
            int g = jr >> 5, jl = jr & 31;
            int jc = g*256 + j0 + jl;
            const float* wp = Whh + ((size_t)d*1024 + jc)*HD + k0 + half*32;
            #pragma unroll
            for (int u4 = 0; u4 < 8; ++u4)
                *(float4*)&ws[jr][half*32 + u4*4] = *(const float4*)(wp + u4*4);
        }
        __syncthreads();
        #pragma unroll
        for (int k = 0; k < 64; k += 4) {
            float4 a0 = *(const float4*)&hs[ty][k];
            float4 a1 = *(const float4*)&hs[ty+16][k];
            #pragma unroll
            for (int g = 0; g < 4; ++g) {
                float4 b0 = *(const float4*)&ws[g*32 + tx][k];
                float4 b1 = *(const float4*)&ws[g*32 + tx + 16][k];
                acc[0][0][g] += a0.x*b0.x + a0.y*b0.y + a0.z*b0.z + a0.w*b0.w;
                acc[0][1][g] += a0.x*b1.x + a0.y*b1.y + a0.z*b1.z + a0.w*b1.w;
                acc[1][0][g] += a1.x*b0.x + a1.y*b0.y + a1.z*b0.z + a1.w*b0.w;
                acc[1][1][g] += a1.x*b1.x + a1.y*b1.y + a1.z*b1.z + a1.w*b1.w;
            }
        }
        __syncthreads();
    }
    #pragma unroll
    for (int ni = 0; ni < 2; ++ni) {
        int n = n0 + ty + ni*16;
        if (n >= SP) continue;
        #pragma unroll
        for (int ji = 0; ji < 2; ++ji) {
            int j = j0 + tx + ji*16;
            size_t gb = ((size_t)t_in*SP + n)*2048 + (size_t)d*1024;
            float gi = acc[ni][ji][0] + G[gb + j];
            float gf = acc[ni][ji][1] + G[gb + 256 + j];
            float gg = acc[ni][ji][2] + G[gb + 512 + j];
            float go = acc[ni][ji][3] + G[gb + 768 + j];
            size_t ci_ = ((size_t)d*SP + n)*HD + j;
            float c_old = c_st[ci_];
            float cn = sigmoidf_(gf)*c_old + sigmoidf_(gi)*tanhf(gg);
            float hn = sigmoidf_(go)*tanhf(cn);
            c_st[ci_] = cn;
            h_out[ci_] = hn;
            x_out[((size_t)t_in*SP + n)*512 + d*HD + j] = hn;
        }
    }
}

// ---------------------------------------------------------------------------
// Kernel 4a: scores tile. P[(h*GRP+bl)*SP + qq][kk] = (q.k/8)/rpe for one
// (h, b-local, 64x64 tile). RPE analytic: max(|c1-r0|,|r1-c0|)/2047.
// grid (36, GRP, 8), block 256, 4x4 outputs/thread, K=64.
// ---------------------------------------------------------------------------
__global__ __launch_bounds__(256)
void scores_k(const float* __restrict__ q, const float* __restrict__ k,
              float* __restrict__ P, int g)
{
    const int h = blockIdx.z, bl = blockIdx.y, bg = g*GRP + bl;
    const int q0 = (blockIdx.x / 6) * 64;
    const int k0 = (blockIdx.x % 6) * 64;
    const int tid = threadIdx.x;
    __shared__ float qs[64][68];
    __shared__ float ks[64][68];
    {   // stage both tiles, row-major [row][d]
        int jr = tid >> 2, c16 = (tid & 3) * 16;
        int qq = q0 + jr; if (qq > SP-1) qq = SP-1;
        int kr = k0 + jr; if (kr > SP-1) kr = SP-1;
        const float* qp = &q[((size_t)bg*SP + qq)*512 + h*64 + c16];
        const float* kp = &k[((size_t)bg*SP + kr)*512 + h*64 + c16];
        #pragma unroll
        for (int u = 0; u < 4; ++u) {
            *(float4*)&qs[jr][c16 + u*4] = *(const float4*)(qp + u*4);
            *(float4*)&ks[jr][c16 + u*4] = *(const float4*)(kp + u*4);
        }
    }
    __syncthreads();
    const int tx = tid & 15, ty = tid >> 4;
    float acc[4][4];
    #pragma unroll
    for (int i = 0; i < 4; ++i)
        #pragma unroll
        for (int j = 0; j < 4; ++j) acc[i][j] = 0.0f;
    for (int d4 = 0; d4 < 64; d4 += 4) {
        float4 a[4], b[4];
        #pragma unroll
        for (int i = 0; i < 4; ++i) a[i] = *(const float4*)&qs[ty + 16*i][d4];
        #pragma unroll
        for (int j = 0; j < 4; ++j) b[j] = *(const float4*)&ks[tx + 16*j][d4];
        #pragma unroll
        for (int i = 0; i < 4; ++i)
            #pragma unroll
            for (int j = 0; j < 4; ++j)
                acc[i][j] += a[i].x*b[j].x + a[i].y*b[j].y + a[i].z*b[j].z + a[i].w*b[j].w;
    }
    #pragma unroll
    for (int i = 0; i < 4; ++i) {
        int qq = q0 + ty + 16*i;
        if (qq >= SP) continue;
        int r0 = 6*qq - 1; if (r0 < 0) r0 = 0;
        int r1 = 6*qq + 7; if (r1 > SLEN-1) r1 = SLEN-1;
        size_t rowb = ((size_t)(h*GRP + bl)*SP + qq) * PSTR;
        #pragma unroll
        for (int j = 0; j < 4; ++j) {
            int kk = k0 + tx + 16*j;
            if (kk >= SP) continue;
            int c0 = 6*kk - 1; if (c0 < 0) c0 = 0;
            int c1 = 6*kk + 7;
            int dd1 = c1 - r0; if (dd1 < 0) dd1 = -dd1;
            int dd2 = r1 - c0; if (dd2 < 0) dd2 = -dd2;
            int den = dd1 > dd2 ? dd1 : dd2;
            P[rowb + kk] = (acc[i][j] * 0.125f) * 2047.0f / (float)den;
        }
    }
}

// ---------------------------------------------------------------------------
// Kernel 4b: row softmax in place. One wave per row of P (length SP, stride PSTR).
// grid = GRP*8*SP/4 blocks of 256 (4 waves).
// ---------------------------------------------------------------------------
__global__ __launch_bounds__(256)
void softmax_k(float* __restrict__ P)
{
    const int tid = threadIdx.x;
    const int row = blockIdx.x * 4 + (tid >> 6);
    const int lane = tid & 63;
    float* rp = P + (size_t)row * PSTR;
    float v[6];
    float m = -1e30f;
    #pragma unroll
    for (int i = 0; i < 6; ++i) {
        int col = lane + 64*i;
        v[i] = (col < SP) ? rp[col] : -1e30f;
        m = fmaxf(m, v[i]);
    }
    #pragma unroll
    for (int o = 1; o < 64; o <<= 1) m = fmaxf(m, __shfl_xor(m, o, 64));
    float s = 0.0f;
    #pragma unroll
    for (int i = 0; i < 6; ++i) {
        v[i] = expf(v[i] - m);     // exp(-1e30-m) underflows to 0 for pad lanes
        s += v[i];
    }
    #pragma unroll
    for (int o = 1; o < 64; o <<= 1) s += __shfl_xor(s, o, 64);
    float inv = 1.0f / s;
    #pragma unroll
    for (int i = 0; i < 6; ++i) {
        int col = lane + 64*i;
        if (col < SP) rp[col] = v[i] * inv;
    }
}

// ---------------------------------------------------------------------------
// Kernel 4c: out = relu(P @ V) for one (h, b-local, 64-q tile). K=SP in 6x64 chunks.
// P staged k-major (transposed), V staged row-major (k-major already). 4x4/thread.
// ---------------------------------------------------------------------------
__global__ __launch_bounds__(256)
void pv_k(const float* __restrict__ P, const float* __restrict__ v,
          float* __restrict__ cat, int g)
{
    const int h = blockIdx.z, bl = blockIdx.y, bg = g*GRP + bl;
    const int q0 = blockIdx.x * 64;
    const int tid = threadIdx.x;
    __shared__ float ps[64][68];   // [k][q]
    __shared__ float vs[64][68];   // [k][d]
    const int tx = tid & 15, ty = tid >> 4;
    float acc[4][4];
    #pragma unroll
    for (int i = 0; i < 4; ++i)
        #pragma unroll
        for (int j = 0; j < 4; ++j) acc[i][j] = 0.0f;

    for (int kc = 0; kc < 6; ++kc) {
        const int kk0 = kc * 64;
        {   // stage P tile transposed: thread reads row (q0+jr), 16 cols; writes ps[col][jr]
            int jr = tid >> 2, c16 = (tid & 3) * 16;
            int qq = q0 + jr; if (qq > SP-1) qq = SP-1;
            const float* pp = P + ((size_t)(h*GRP + bl)*SP + qq)*PSTR + kk0 + c16;
            #pragma unroll
            for (int u = 0; u < 4; ++u) {
                float4 w = *(const float4*)(pp + u*4);
                int klb = c16 + u*4;
                float vals[4] = {w.x, w.y, w.z, w.w};
                #pragma unroll
                for (int e = 0; e < 4; ++e)
                    ps[klb + e][jr] = (kk0 + klb + e < SP) ? vals[e] : 0.0f;
            }
        }
        {   // stage V chunk [k][d] direct
            int jr = tid >> 2, c16 = (tid & 3) * 16;
            int kr = kk0 + jr; if (kr > SP-1) kr = SP-1;
            const float* vp = &v[((size_t)bg*SP + kr)*512 + h*64 + c16];
            #pragma unroll
            for (int u = 0; u < 4; ++u)
                *(float4*)&vs[jr][c16 + u*4] = *(const float4*)(vp + u*4);
        }
        __syncthreads();
        for (int kk = 0; kk < 64; ++kk) {
            float4 a4 = *(const float4*)&ps[kk][ty*4];
            float4 b4 = *(const float4*)&vs[kk][tx*4];
            float av[4] = {a4.x, a4.y, a4.z, a4.w};
            float bv[4] = {b4.x, b4.y, b4.z, b4.w};
            #pragma unroll
            for (int i = 0; i < 4; ++i)
                #pragma unroll
                for (int j = 0; j < 4; ++j)
                    acc[i][j] += av[i] * bv[j];
        }
        __syncthreads();
    }
    #pragma unroll
    for (int i = 0; i < 4; ++i) {
        int qq = q0 + ty*4 + i;
        if (qq >= SP) continue;
        float4 r;
        r.x = fmaxf(acc[i][0], 0.0f);
        r.y = fmaxf(acc[i][1], 0.0f);
        r.z = fmaxf(acc[i][2], 0.0f);
        r.w = fmaxf(acc[i][3], 0.0f);
        *(float4*)&cat[((size_t)bg*SP + qq)*512 + h*64 + tx*4] = r;
    }
}

// ---------------------------------------------------------------------------
extern "C" void kernel_launch(void* const* d_in, const int* in_sizes, int n_in,
                              void* d_out, int out_size, void* d_ws, size_t ws_size,
                              hipStream_t stream)
{
    (void)in_sizes; (void)n_in; (void)out_size; (void)ws_size;
    const float* in    = (const float*)d_in[0];
    const float* cw    = (const float*)d_in[1];
    const float* gamma = (const float*)d_in[2];
    const float* beta  = (const float*)d_in[3];
    const float* Wih0  = (const float*)d_in[4];
    const float* Whh0  = (const float*)d_in[5];
    const float* b0    = (const float*)d_in[6];
    const float* Wih1  = (const float*)d_in[7];
    const float* Whh1  = (const float*)d_in[8];
    const float* b1    = (const float*)d_in[9];
    const float* Qw    = (const float*)d_in[10];
    const float* Qb    = (const float*)d_in[11];
    const float* Kw    = (const float*)d_in[12];
    const float* Kb    = (const float*)d_in[13];
    const float* Vw    = (const float*)d_in[14];
    const float* Vb    = (const float*)d_in[15];
    const float* mhw   = (const float*)d_in[16];
    const float* mhb   = (const float*)d_in[17];
    float* out = (float*)d_out;

    // workspace arena (floats). Total ~149 MB.
    float* x0 = (float*)d_ws;                                   //  2,793,472
    float* G  = x0 + (size_t)RTOT*NF;                           // 22,347,776 (reused for q,k,v + P)
    float* x1 = G  + (size_t)RTOT*2048;                         //  5,586,944 (reused for cat)
    float* x2 = x1 + (size_t)RTOT*512;                          //  5,586,944
    float* hb = x2 + (size_t)RTOT*512;                          //  2 * 174,592 (h double buffer)
    float* cb = hb + (size_t)2*2*SP*HD;                         //  174,592
    float* qbuf = G;
    float* kbuf = G + (size_t)RTOT*512;
    float* vbuf = G + (size_t)2*RTOT*512;
    float* P    = G + (size_t)3*RTOT*512;   // 22.3 MB free tail; P needs 15.0 MB
    float* cat  = x1;
    const size_t hsz = (size_t)2*SP*HD;

    // 1. conv+bn+relu+pool
    conv_pool_k<<<dim3(22, B_), 256, 0, stream>>>(in, cw, gamma, beta, x0);
    // 2. layer-1 input gates: G = x0 @ Wih0^T + b0   [10912 x 2048], K=256
    gemm_k<0><<<dim3(16, 86), 256, 0, stream>>>(x0, Wih0, b0, G, RTOT, 2048, 256);
    // 3. layer-1 scan (32 steps, both dirs)
    hipMemsetAsync(hb, 0, 2*hsz*sizeof(float), stream);
    hipMemsetAsync(cb, 0, hsz*sizeof(float), stream);
    for (int s = 0; s < B_; ++s) {
        float* hin  = hb + (size_t)(s & 1) * hsz;
        float* hout = hb + (size_t)((s+1) & 1) * hsz;
        lstm_step_k<<<dim3(8, 11, 2), 256, 0, stream>>>(G, Whh0, hin, hout, cb, x1, s);
    }
    // 4. layer-2 input gates: G = x1 @ Wih1^T + b1, K=512
    gemm_k<0><<<dim3(16, 86), 256, 0, stream>>>(x1, Wih1, b1, G, RTOT, 2048, 512);
    // 5. layer-2 scan
    hipMemsetAsync(hb, 0, 2*hsz*sizeof(float), stream);
    hipMemsetAsync(cb, 0, hsz*sizeof(float), stream);
    for (int s = 0; s < B_; ++s) {
        float* hin  = hb + (size_t)(s & 1) * hsz;
        float* hout = hb + (size_t)((s+1) & 1) * hsz;
        lstm_step_k<<<dim3(8, 11, 2), 256, 0, stream>>>(G, Whh1, hin, hout, cb, x2, s);
    }
    // 6. Q/K/V projections (flattened per-head weights are plain [512][512] GEMMs)
    gemm_k<0><<<dim3(4, 86), 256, 0, stream>>>(x2, Qw, Qb, qbuf, RTOT, 512, 512);
    gemm_k<0><<<dim3(4, 86), 256, 0, stream>>>(x2, Kw, Kb, kbuf, RTOT, 512, 512);
    gemm_k<0><<<dim3(4, 86), 256, 0, stream>>>(x2, Vw, Vb, vbuf, RTOT, 512, 512);
    // 7. attention in GRP-batch groups: scores -> softmax -> PV
    for (int g = 0; g < B_/GRP; ++g) {
        scores_k <<<dim3(36, GRP, NH_), 256, 0, stream>>>(qbuf, kbuf, P, g);
        softmax_k<<<dim3(NH_*GRP*SP/4), 256, 0, stream>>>(P);
        pv_k     <<<dim3(6, GRP, NH_), 256, 0, stream>>>(P, vbuf, cat, g);
    }
    // 8. final linear + relu -> out
    gemm_k<1><<<dim3(4, 86), 256, 0, stream>>>(cat, mhw, mhb, out, RTOT, 512, 512);
}

// Round 6
// 2167.943 us; speedup vs baseline: 3.5303x; 1.2475x over previous
//
#include <hip/hip_runtime.h>
#include <math.h>

// Problem constants
#define B_    32
#define CIN   4
#define SLEN  2048
#define NF    256
#define HD    256          // LSTM hidden per direction
#define SP    341          // post conv+pool sequence length
#define RTOT  (B_*SP)      // 10912 rows
#define NH_   8
#define DH_   64
#define GRP   4            // batches per attention group
#define PSTR  344          // padded P row stride (16B-aligned)
#define HS    (SP*HD)      // 87296: per-dir h elems

typedef __attribute__((ext_vector_type(8))) short short8;
typedef __attribute__((ext_vector_type(4))) float floatx4;

__device__ __forceinline__ float sigmoidf_(float x) { return 1.0f / (1.0f + expf(-x)); }

__device__ __forceinline__ unsigned short f2bf(float x) {
    unsigned int u = __float_as_uint(x);
    unsigned int r = (u + 0x7FFF + ((u >> 16) & 1)) >> 16;   // RNE
    return (unsigned short)r;
}
__device__ __forceinline__ float bf2f(unsigned short b) {
    return __uint_as_float(((unsigned int)b) << 16);
}

// ---------------------------------------------------------------------------
// Kernel 1: Conv1d(4->256,k13,pad6) + BN(eval) + ReLU + MaxPool1d(6) -> x0[b*341+s][co]
// ---------------------------------------------------------------------------
__global__ __launch_bounds__(256)
void conv_pool_k(const float* __restrict__ in, const float* __restrict__ cw,
                 const float* __restrict__ gamma, const float* __restrict__ beta,
                 float* __restrict__ x0)
{
    const int b  = blockIdx.y;
    const int s0 = blockIdx.x * 16;
    const int co = threadIdx.x;
    __shared__ float ins[CIN][16*6 + 12];
    for (int idx = threadIdx.x; idx < CIN*108; idx += 256) {
        int ci = idx / 108, o = idx % 108;
        int pos = 6*s0 - 6 + o;
        ins[ci][o] = (pos >= 0 && pos < SLEN) ? in[(b*CIN + ci)*SLEN + pos] : 0.0f;
    }
    float wreg[52];
    {
        const float4* wp = (const float4*)(cw + co*52);
        #pragma unroll
        for (int j4 = 0; j4 < 13; ++j4) {
            float4 w4 = wp[j4];
            wreg[j4*4+0]=w4.x; wreg[j4*4+1]=w4.y; wreg[j4*4+2]=w4.z; wreg[j4*4+3]=w4.w;
        }
    }
    const float scale = gamma[co] * (1.0f / sqrtf(1.0f + 1e-5f));
    const float shift = beta[co];
    __syncthreads();
    for (int si = 0; si < 16; ++si) {
        int s = s0 + si;
        if (s >= SP) break;
        float win[CIN][18];
        #pragma unroll
        for (int ci = 0; ci < CIN; ++ci)
            #pragma unroll
            for (int o = 0; o < 18; ++o)
                win[ci][o] = ins[ci][6*si + o];
        float m = -1e30f;
        #pragma unroll
        for (int p6 = 0; p6 < 6; ++p6) {
            float acc = 0.0f;
            #pragma unroll
            for (int ci = 0; ci < CIN; ++ci)
                #pragma unroll
                for (int kk = 0; kk < 13; ++kk)
                    acc += win[ci][p6+kk] * wreg[ci*13+kk];
            float val = acc * scale + shift;
            val = fmaxf(val, 0.0f);
            m = fmaxf(m, val);
        }
        x0[(size_t)(b*SP + s)*NF + co] = m;
    }
}

// ---------------------------------------------------------------------------
// Kernel 2: generic fp32 GEMM  C[M,N] = act(A[M,K] @ Bw[N,K]^T + bias[N])
// ---------------------------------------------------------------------------
template<int RELU>
__global__ __launch_bounds__(256)
void gemm_k(const float* __restrict__ A, const float* __restrict__ Bw,
            const float* __restrict__ bias, float* __restrict__ C,
            int M, int N, int K)
{
    const int n0 = blockIdx.x * 128;
    const int m0 = blockIdx.y * 128;
    const int tid = threadIdx.x;
    const int tx = tid % 16, ty = tid / 16;
    __shared__ float As[16][132];
    __shared__ float Bs[16][132];
    float acc[8][8];
    #pragma unroll
    for (int i = 0; i < 8; ++i)
        #pragma unroll
        for (int j = 0; j < 8; ++j) acc[i][j] = 0.0f;

    const int lr = tid >> 1;
    const int lc = (tid & 1) * 8;

    for (int k0 = 0; k0 < K; k0 += 16) {
        {
            int gm = m0 + lr; if (gm >= M) gm = M - 1;
            const float* ap = A + (size_t)gm*K + k0 + lc;
            float4 v0 = *(const float4*)ap;
            float4 v1 = *(const float4*)(ap + 4);
            As[lc+0][lr]=v0.x; As[lc+1][lr]=v0.y; As[lc+2][lr]=v0.z; As[lc+3][lr]=v0.w;
            As[lc+4][lr]=v1.x; As[lc+5][lr]=v1.y; As[lc+6][lr]=v1.z; As[lc+7][lr]=v1.w;
            const float* bp = Bw + (size_t)(n0 + lr)*K + k0 + lc;
            float4 u0 = *(const float4*)bp;
            float4 u1 = *(const float4*)(bp + 4);
            Bs[lc+0][lr]=u0.x; Bs[lc+1][lr]=u0.y; Bs[lc+2][lr]=u0.z; Bs[lc+3][lr]=u0.w;
            Bs[lc+4][lr]=u1.x; Bs[lc+5][lr]=u1.y; Bs[lc+6][lr]=u1.z; Bs[lc+7][lr]=u1.w;
        }
        __syncthreads();
        #pragma unroll
        for (int k = 0; k < 16; ++k) {
            float4 a0 = *(const float4*)&As[k][ty*4];
            float4 a1 = *(const float4*)&As[k][ty*4 + 64];
            float4 b0 = *(const float4*)&Bs[k][tx*4];
            float4 b1 = *(const float4*)&Bs[k][tx*4 + 64];
            float av[8] = {a0.x,a0.y,a0.z,a0.w,a1.x,a1.y,a1.z,a1.w};
            float bv[8] = {b0.x,b0.y,b0.z,b0.w,b1.x,b1.y,b1.z,b1.w};
            #pragma unroll
            for (int i = 0; i < 8; ++i)
                #pragma unroll
                for (int j = 0; j < 8; ++j)
                    acc[i][j] += av[i] * bv[j];
        }
        __syncthreads();
    }
    #pragma unroll
    for (int ih = 0; ih < 2; ++ih) {
        #pragma unroll
        for (int ii = 0; ii < 4; ++ii) {
            int m = m0 + ih*64 + ty*4 + ii;
            if (m >= M) continue;
            #pragma unroll
            for (int jh = 0; jh < 2; ++jh) {
                int n = n0 + jh*64 + tx*4;
                float4 bb = *(const float4*)&bias[n];
                float4 r;
                r.x = acc[ih*4+ii][jh*4+0] + bb.x;
                r.y = acc[ih*4+ii][jh*4+1] + bb.y;
                r.z = acc[ih*4+ii][jh*4+2] + bb.z;
                r.w = acc[ih*4+ii][jh*4+3] + bb.w;
                if (RELU) {
                    r.x = fmaxf(r.x, 0.f); r.y = fmaxf(r.y, 0.f);
                    r.z = fmaxf(r.z, 0.f); r.w = fmaxf(r.w, 0.f);
                }
                *(float4*)&C[(size_t)m*N + n] = r;
            }
        }
    }
}

// ---------------------------------------------------------------------------
// Kernel 3a: pack fp32 weights -> bf16 hi/lo pair (same row-major layout)
// ---------------------------------------------------------------------------
__global__ __launch_bounds__(256)
void pack_whh_k(const float* __restrict__ W, unsigned short* __restrict__ hi,
                unsigned short* __restrict__ lo, int n)
{
    int i = blockIdx.x * 256 + threadIdx.x;
    if (i < n) {
        float x = W[i];
        unsigned short h = f2bf(x);
        hi[i] = h;
        lo[i] = f2bf(x - bf2f(h));
    }
}

// ---------------------------------------------------------------------------
// Kernel 3b: one LSTM step via split-bf16 MFMA. h state stays fp32 in the R3
// double buffers; hi/lo split of h happens in-register each step.
// grid (8 j-tiles, 11 m-tiles, 2 dirs), 256 thr (4 waves).
// C[32m x 128(4g x 32j)] = h @ Whh^T via mfma_f32_16x16x32_bf16:
//   hi*hi + hi*lo + lo*hi  (lo*lo dropped, ~2^-16 rel).
// A-frag: m=lane&15, k=quad*8+j (8 consecutive fp32 -> split). B-frag: W row
// nrow (=output col), same k — gives D[m][n] = sum_k h[m][k]*W[n][k].
// D layout col=lane&15, row=quad*4+reg -> LDS -> cell-update epilogue (as R3).
// ---------------------------------------------------------------------------
__global__ __launch_bounds__(256)
void lstm_step_mfma_k(const float* __restrict__ G,              // [32*341][2048]
                      const unsigned short* __restrict__ Whi,   // [2][1024][256]
                      const unsigned short* __restrict__ Wlo,
                      const float* __restrict__ h_in,           // [2][341][256] fp32
                      float* __restrict__ h_out,
                      float* __restrict__ c_st,                 // [2][341][256]
                      float* __restrict__ x_out,                // [32*341][512]
                      int s)
{
    const int j0 = blockIdx.x * 32;
    const int m0 = blockIdx.y * 32;
    const int d  = blockIdx.z;
    const int t_in = d ? (B_ - 1 - s) : s;
    const int tid = threadIdx.x;
    const int w = tid >> 6, lane = tid & 63;
    const int mhalf = w & 1, gpair = w >> 1;
    const int ln15 = lane & 15, lq = lane >> 4;

    __shared__ float Csh[32][132];

    int am = m0 + mhalf*16 + ln15; if (am > SP-1) am = SP-1;   // A row (clamped)
    const int akoff = lq * 8;
    const float* hA = h_in + (size_t)d*HS + (size_t)am*HD;

    const unsigned short* WhiD = Whi + (size_t)d*1024*256;
    const unsigned short* WloD = Wlo + (size_t)d*1024*256;
    int nrow[4];   // Whh row (output col) per n-subtile: gates {2*gpair,2*gpair+1} x j-halves
    #pragma unroll
    for (int t = 0; t < 4; ++t)
        nrow[t] = (gpair*2 + (t>>1))*256 + j0 + (t&1)*16 + ln15;

    floatx4 acc[4];
    #pragma unroll
    for (int t = 0; t < 4; ++t) acc[t] = (floatx4){0.f, 0.f, 0.f, 0.f};

    #pragma unroll
    for (int kk = 0; kk < 8; ++kk) {
        const int ko = kk*32 + akoff;
        float4 v0 = *(const float4*)(hA + ko);
        float4 v1 = *(const float4*)(hA + ko + 4);
        float vv[8] = {v0.x, v0.y, v0.z, v0.w, v1.x, v1.y, v1.z, v1.w};
        short8 ahi, alo;
        #pragma unroll
        for (int e = 0; e < 8; ++e) {
            unsigned short hb16 = f2bf(vv[e]);
            ahi[e] = (short)hb16;
            alo[e] = (short)f2bf(vv[e] - bf2f(hb16));
        }
        #pragma unroll
        for (int t = 0; t < 4; ++t) {
            short8 bhi = *(const short8*)(WhiD + (size_t)nrow[t]*HD + ko);
            short8 blo = *(const short8*)(WloD + (size_t)nrow[t]*HD + ko);
            acc[t] = __builtin_amdgcn_mfma_f32_16x16x32_bf16(alo, bhi, acc[t], 0, 0, 0);
            acc[t] = __builtin_amdgcn_mfma_f32_16x16x32_bf16(ahi, blo, acc[t], 0, 0, 0);
            acc[t] = __builtin_amdgcn_mfma_f32_16x16x32_bf16(ahi, bhi, acc[t], 0, 0, 0);
        }
    }

    // dump C fragments to LDS (D: col=lane&15, row=lq*4+reg)
    #pragma unroll
    for (int t = 0; t < 4; ++t) {
        int col = gpair*64 + (t>>1)*32 + (t&1)*16 + ln15;
        int rb  = mhalf*16 + lq*4;
        #pragma unroll
        for (int r = 0; r < 4; ++r)
            Csh[rb + r][col] = acc[t][r];
    }
    __syncthreads();

    const int emloc = tid >> 3;           // 0..31 local row
    const int ej4   = (tid & 7) * 4;      // 0..28 local col (x4)
    const int em    = m0 + emloc;
    if (em < SP) {
        size_t gb = ((size_t)t_in*SP + em)*2048 + (size_t)d*1024 + j0 + ej4;
        float4 gi4 = *(const float4*)&G[gb];
        float4 gf4 = *(const float4*)&G[gb + 256];
        float4 gg4 = *(const float4*)&G[gb + 512];
        float4 go4 = *(const float4*)&G[gb + 768];
        size_t cbase = ((size_t)d*SP + em)*HD + j0 + ej4;
        float4 cold = *(float4*)&c_st[cbase];
        float hv[4];
        #pragma unroll
        for (int e = 0; e < 4; ++e) {
            float gi = Csh[emloc][     ej4+e] + (&gi4.x)[e];
            float gf = Csh[emloc][32 + ej4+e] + (&gf4.x)[e];
            float gg = Csh[emloc][64 + ej4+e] + (&gg4.x)[e];
            float go = Csh[emloc][96 + ej4+e] + (&go4.x)[e];
            float cn = sigmoidf_(gf)*(&cold.x)[e] + sigmoidf_(gi)*tanhf(gg);
            (&cold.x)[e] = cn;
            hv[e] = sigmoidf_(go)*tanhf(cn);
        }
        *(float4*)&c_st[cbase] = cold;
        float4 ho; ho.x = hv[0]; ho.y = hv[1]; ho.z = hv[2]; ho.w = hv[3];
        *(float4*)&h_out[cbase] = ho;
        *(float4*)&x_out[((size_t)t_in*SP + em)*512 + d*HD + j0 + ej4] = ho;
    }
}

// ---------------------------------------------------------------------------
// Kernel 4a: scores tile (64x64), RPE analytic.
// ---------------------------------------------------------------------------
__global__ __launch_bounds__(256)
void scores_k(const float* __restrict__ q, const float* __restrict__ k,
              float* __restrict__ P, int g)
{
    const int h = blockIdx.z, bl = blockIdx.y, bg = g*GRP + bl;
    const int q0 = (blockIdx.x / 6) * 64;
    const int k0 = (blockIdx.x % 6) * 64;
    const int tid = threadIdx.x;
    __shared__ float qs[64][68];
    __shared__ float ks[64][68];
    {
        int jr = tid >> 2, c16 = (tid & 3) * 16;
        int qq = q0 + jr; if (qq > SP-1) qq = SP-1;
        int kr = k0 + jr; if (kr > SP-1) kr = SP-1;
        const float* qp = &q[((size_t)bg*SP + qq)*512 + h*64 + c16];
        const float* kp = &k[((size_t)bg*SP + kr)*512 + h*64 + c16];
        #pragma unroll
        for (int u = 0; u < 4; ++u) {
            *(float4*)&qs[jr][c16 + u*4] = *(const float4*)(qp + u*4);
            *(float4*)&ks[jr][c16 + u*4] = *(const float4*)(kp + u*4);
        }
    }
    __syncthreads();
    const int tx = tid & 15, ty = tid >> 4;
    float acc[4][4];
    #pragma unroll
    for (int i = 0; i < 4; ++i)
        #pragma unroll
        for (int j = 0; j < 4; ++j) acc[i][j] = 0.0f;
    for (int d4 = 0; d4 < 64; d4 += 4) {
        float4 a[4], b[4];
        #pragma unroll
        for (int i = 0; i < 4; ++i) a[i] = *(const float4*)&qs[ty + 16*i][d4];
        #pragma unroll
        for (int j = 0; j < 4; ++j) b[j] = *(const float4*)&ks[tx + 16*j][d4];
        #pragma unroll
        for (int i = 0; i < 4; ++i)
            #pragma unroll
            for (int j = 0; j < 4; ++j)
                acc[i][j] += a[i].x*b[j].x + a[i].y*b[j].y + a[i].z*b[j].z + a[i].w*b[j].w;
    }
    #pragma unroll
    for (int i = 0; i < 4; ++i) {
        int qq = q0 + ty + 16*i;
        if (qq >= SP) continue;
        int r0 = 6*qq - 1; if (r0 < 0) r0 = 0;
        int r1 = 6*qq + 7; if (r1 > SLEN-1) r1 = SLEN-1;
        size_t rowb = ((size_t)(h*GRP + bl)*SP + qq) * PSTR;
        #pragma unroll
        for (int j = 0; j < 4; ++j) {
            int kk = k0 + tx + 16*j;
            if (kk >= SP) continue;
            int c0 = 6*kk - 1; if (c0 < 0) c0 = 0;
            int c1 = 6*kk + 7;
            int dd1 = c1 - r0; if (dd1 < 0) dd1 = -dd1;
            int dd2 = r1 - c0; if (dd2 < 0) dd2 = -dd2;
            int den = dd1 > dd2 ? dd1 : dd2;
            P[rowb + kk] = (acc[i][j] * 0.125f) * 2047.0f / (float)den;
        }
    }
}

// ---------------------------------------------------------------------------
// Kernel 4b: row softmax in place.
// ---------------------------------------------------------------------------
__global__ __launch_bounds__(256)
void softmax_k(float* __restrict__ P)
{
    const int tid = threadIdx.x;
    const int row = blockIdx.x * 4 + (tid >> 6);
    const int lane = tid & 63;
    float* rp = P + (size_t)row * PSTR;
    float v[6];
    float m = -1e30f;
    #pragma unroll
    for (int i = 0; i < 6; ++i) {
        int col = lane + 64*i;
        v[i] = (col < SP) ? rp[col] : -1e30f;
        m = fmaxf(m, v[i]);
    }
    #pragma unroll
    for (int o = 1; o < 64; o <<= 1) m = fmaxf(m, __shfl_xor(m, o, 64));
    float s = 0.0f;
    #pragma unroll
    for (int i = 0; i < 6; ++i) {
        v[i] = expf(v[i] - m);
        s += v[i];
    }
    #pragma unroll
    for (int o = 1; o < 64; o <<= 1) s += __shfl_xor(s, o, 64);
    float inv = 1.0f / s;
    #pragma unroll
    for (int i = 0; i < 6; ++i) {
        int col = lane + 64*i;
        if (col < SP) rp[col] = v[i] * inv;
    }
}

// ---------------------------------------------------------------------------
// Kernel 4c: out = relu(P @ V), K=SP in 6x64 chunks.
// ---------------------------------------------------------------------------
__global__ __launch_bounds__(256)
void pv_k(const float* __restrict__ P, const float* __restrict__ v,
          float* __restrict__ cat, int g)
{
    const int h = blockIdx.z, bl = blockIdx.y, bg = g*GRP + bl;
    const int q0 = blockIdx.x * 64;
    const int tid = threadIdx.x;
    __shared__ float ps[64][68];
    __shared__ float vs[64][68];
    const int tx = tid & 15, ty = tid >> 4;
    float acc[4][4];
    #pragma unroll
    for (int i = 0; i < 4; ++i)
        #pragma unroll
        for (int j = 0; j < 4; ++j) acc[i][j] = 0.0f;

    for (int kc = 0; kc < 6; ++kc) {
        const int kk0 = kc * 64;
        {
            int jr = tid >> 2, c16 = (tid & 3) * 16;
            int qq = q0 + jr; if (qq > SP-1) qq = SP-1;
            const float* pp = P + ((size_t)(h*GRP + bl)*SP + qq)*PSTR + kk0 + c16;
            #pragma unroll
            for (int u = 0; u < 4; ++u) {
                float4 w = *(const float4*)(pp + u*4);
                int klb = c16 + u*4;
                float vals[4] = {w.x, w.y, w.z, w.w};
                #pragma unroll
                for (int e = 0; e < 4; ++e)
                    ps[klb + e][jr] = (kk0 + klb + e < SP) ? vals[e] : 0.0f;
            }
        }
        {
            int jr = tid >> 2, c16 = (tid & 3) * 16;
            int kr = kk0 + jr; if (kr > SP-1) kr = SP-1;
            const float* vp = &v[((size_t)bg*SP + kr)*512 + h*64 + c16];
            #pragma unroll
            for (int u = 0; u < 4; ++u)
                *(float4*)&vs[jr][c16 + u*4] = *(const float4*)(vp + u*4);
        }
        __syncthreads();
        for (int kk = 0; kk < 64; ++kk) {
            float4 a4 = *(const float4*)&ps[kk][ty*4];
            float4 b4 = *(const float4*)&vs[kk][tx*4];
            float av[4] = {a4.x, a4.y, a4.z, a4.w};
            float bv[4] = {b4.x, b4.y, b4.z, b4.w};
            #pragma unroll
            for (int i = 0; i < 4; ++i)
                #pragma unroll
                for (int j = 0; j < 4; ++j)
                    acc[i][j] += av[i] * bv[j];
        }
        __syncthreads();
    }
    #pragma unroll
    for (int i = 0; i < 4; ++i) {
        int qq = q0 + ty*4 + i;
        if (qq >= SP) continue;
        float4 r;
        r.x = fmaxf(acc[i][0], 0.0f);
        r.y = fmaxf(acc[i][1], 0.0f);
        r.z = fmaxf(acc[i][2], 0.0f);
        r.w = fmaxf(acc[i][3], 0.0f);
        *(float4*)&cat[((size_t)bg*SP + qq)*512 + h*64 + tx*4] = r;
    }
}

// ---------------------------------------------------------------------------
extern "C" void kernel_launch(void* const* d_in, const int* in_sizes, int n_in,
                              void* d_out, int out_size, void* d_ws, size_t ws_size,
                              hipStream_t stream)
{
    (void)in_sizes; (void)n_in; (void)out_size; (void)ws_size;
    const float* in    = (const float*)d_in[0];
    const float* cw    = (const float*)d_in[1];
    const float* gamma = (const float*)d_in[2];
    const float* beta  = (const float*)d_in[3];
    const float* Wih0  = (const float*)d_in[4];
    const float* Whh0  = (const float*)d_in[5];
    const float* b0    = (const float*)d_in[6];
    const float* Wih1  = (const float*)d_in[7];
    const float* Whh1  = (const float*)d_in[8];
    const float* b1    = (const float*)d_in[9];
    const float* Qw    = (const float*)d_in[10];
    const float* Qb    = (const float*)d_in[11];
    const float* Kw    = (const float*)d_in[12];
    const float* Kb    = (const float*)d_in[13];
    const float* Vw    = (const float*)d_in[14];
    const float* Vb    = (const float*)d_in[15];
    const float* mhw   = (const float*)d_in[16];
    const float* mhb   = (const float*)d_in[17];
    float* out = (float*)d_out;

    // workspace arena (floats). Total 147.36 MB — EXACT R3 memory map.
    float* x0 = (float*)d_ws;                                   //  2,793,472 f (packs live here after use)
    float* G  = x0 + (size_t)RTOT*NF;                           // 22,347,776 f (reused q,k,v + P)
    float* x1 = G  + (size_t)RTOT*2048;                         //  5,586,944 f (reused cat)
    float* x2 = x1 + (size_t)RTOT*512;                          //  5,586,944 f
    float* hb = x2 + (size_t)RTOT*512;                          //  349,184 f (fp32 h double buffer, as R3)
    float* cb = hb + (size_t)2*2*SP*HD;                         //  174,592 f (c state)
    // Whh bf16 hi/lo pack arrays in x0's space (x0 dead after the first G-GEMM):
    unsigned short* whh_hi0 = (unsigned short*)x0;              // 524,288 ush each
    unsigned short* whh_lo0 = whh_hi0 + (size_t)2*1024*256;
    unsigned short* whh_hi1 = whh_lo0 + (size_t)2*1024*256;
    unsigned short* whh_lo1 = whh_hi1 + (size_t)2*1024*256;     // 4.19 MB < x0's 11.17 MB
    float* qbuf = G;
    float* kbuf = G + (size_t)RTOT*512;
    float* vbuf = G + (size_t)2*RTOT*512;
    float* P    = G + (size_t)3*RTOT*512;
    float* cat  = x1;
    const size_t hsz = (size_t)2*SP*HD;

    // 1. conv+bn+relu+pool
    conv_pool_k<<<dim3(22, B_), 256, 0, stream>>>(in, cw, gamma, beta, x0);
    // 2. layer-1 input gates: G = x0 @ Wih0^T + b0  (consumes x0)
    gemm_k<0><<<dim3(16, 86), 256, 0, stream>>>(x0, Wih0, b0, G, RTOT, 2048, 256);
    // 2b. pack Whh -> bf16 hi/lo into x0's space (stream-ordered after gemm#1)
    pack_whh_k<<<dim3(2048), 256, 0, stream>>>(Whh0, whh_hi0, whh_lo0, 2*1024*256);
    pack_whh_k<<<dim3(2048), 256, 0, stream>>>(Whh1, whh_hi1, whh_lo1, 2*1024*256);
    // 3. layer-1 scan (32 MFMA steps, fp32 h double buffer as R3)
    hipMemsetAsync(hb, 0, 2*hsz*sizeof(float), stream);
    hipMemsetAsync(cb, 0, hsz*sizeof(float), stream);
    for (int s = 0; s < B_; ++s) {
        float* hin  = hb + (size_t)(s & 1) * hsz;
        float* hout = hb + (size_t)((s+1) & 1) * hsz;
        lstm_step_mfma_k<<<dim3(8, 11, 2), 256, 0, stream>>>(
            G, whh_hi0, whh_lo0, hin, hout, cb, x1, s);
    }
    // 4. layer-2 input gates
    gemm_k<0><<<dim3(16, 86), 256, 0, stream>>>(x1, Wih1, b1, G, RTOT, 2048, 512);
    // 5. layer-2 scan
    hipMemsetAsync(hb, 0, 2*hsz*sizeof(float), stream);
    hipMemsetAsync(cb, 0, hsz*sizeof(float), stream);
    for (int s = 0; s < B_; ++s) {
        float* hin  = hb + (size_t)(s & 1) * hsz;
        float* hout = hb + (size_t)((s+1) & 1) * hsz;
        lstm_step_mfma_k<<<dim3(8, 11, 2), 256, 0, stream>>>(
            G, whh_hi1, whh_lo1, hin, hout, cb, x2, s);
    }
    // 6. Q/K/V projections
    gemm_k<0><<<dim3(4, 86), 256, 0, stream>>>(x2, Qw, Qb, qbuf, RTOT, 512, 512);
    gemm_k<0><<<dim3(4, 86), 256, 0, stream>>>(x2, Kw, Kb, kbuf, RTOT, 512, 512);
    gemm_k<0><<<dim3(4, 86), 256, 0, stream>>>(x2, Vw, Vb, vbuf, RTOT, 512, 512);
    // 7. attention in GRP-batch groups
    for (int g = 0; g < B_/GRP; ++g) {
        scores_k <<<dim3(36, GRP, NH_), 256, 0, stream>>>(qbuf, kbuf, P, g);
        softmax_k<<<dim3(NH_*GRP*SP/4), 256, 0, stream>>>(P);
        pv_k     <<<dim3(6, GRP, NH_), 256, 0, stream>>>(P, vbuf, cat, g);
    }
    // 8. final linear + relu
    gemm_k<1><<<dim3(4, 86), 256, 0, stream>>>(cat, mhw, mhb, out, RTOT, 512, 512);
}